// Round 4
// baseline (58.001 us; speedup 1.0000x reference)
//
#include <hip/hip_runtime.h>

// PCEN over x[B=64, M=128, T=4000] fp32, T contiguous.
// n_t = A*n_{t-1} + x_t  (n = m/S, A=0.975, S=0.025)
// pcen = sqrt(x*(S*n+eps)^-0.98 + 2) - sqrt(2)
//
// One wave per row; 512 contiguous timesteps per iteration (lane l owns 8
// elems = 2 float4 at [it*512 + 8l] -> 2KB contiguous per wave load/store).
// Linear recurrence as associative scan: 8-step lane-local EMA, 6-step
// shfl_up Hillis-Steele with compile-time decay powers A^8..A^256, then
// per-element recompute from the previous lane's total. Exact algorithm.

#define TT     4000
#define NROWS  8192   // 64*128
#define NFULL  7      // 7*512 = 3584 full batches
#define TAILL  52     // tail: 416 elems = 52 lanes * 8

__global__ __launch_bounds__(256, 8) void pcen_kernel(const float* __restrict__ x,
                                                      float* __restrict__ out) {
    const int wid  = (blockIdx.x * blockDim.x + threadIdx.x) >> 6;  // = row
    const int lane = threadIdx.x & 63;

    const float S = 0.025f, A = 0.975f, EPS = 1e-6f, NA = -0.98f;
    const float SQRT2 = 1.41421356237f;

    // Compile-time decay powers.
    const float A2   = A * A;
    const float A4   = A2 * A2;
    const float A8   = A4 * A4;
    const float A16  = A8 * A8;
    const float A32  = A16 * A16;
    const float A64  = A32 * A32;
    const float A128 = A64 * A64;
    const float A256 = A128 * A128;
    const float A512 = A256 * A256;

    // powAl = A^(8*lane), from lane bits.
    float powAl = 1.0f;
    if (lane & 1)  powAl *= A8;
    if (lane & 2)  powAl *= A16;
    if (lane & 4)  powAl *= A32;
    if (lane & 8)  powAl *= A64;
    if (lane & 16) powAl *= A128;
    if (lane & 32) powAl *= A256;

    const float4* xi = (const float4*)(x   + (long)wid * TT) + 2 * lane;
    float4*       oi = (float4*)      (out + (long)wid * TT) + 2 * lane;

    float carry = 0.0f;  // n-state entering this batch (wave-uniform)

    #pragma unroll 2
    for (int it = 0; it <= NFULL; ++it) {
        const bool active = (it < NFULL) | (lane < TAILL);
        float4 v0 = make_float4(0.f, 0.f, 0.f, 0.f);
        float4 v1 = make_float4(0.f, 0.f, 0.f, 0.f);
        if (active) { v0 = xi[it * 128]; v1 = xi[it * 128 + 1]; }

        // Lane-local 8-step scan from 0 (n-space: no S multiplies).
        float b = v0.x;
        b = fmaf(A, b, v0.y);
        b = fmaf(A, b, v0.z);
        b = fmaf(A, b, v0.w);
        b = fmaf(A, b, v1.x);
        b = fmaf(A, b, v1.y);
        b = fmaf(A, b, v1.z);
        float B = fmaf(A, b, v1.w);   // lane aggregate from state 0

        // Wave inclusive scan; per-lane segment decay A^8.
        float t;
        t = __shfl_up(B, 1, 64);  B = fmaf(A8,   (lane >= 1)  ? t : 0.0f, B);
        t = __shfl_up(B, 2, 64);  B = fmaf(A16,  (lane >= 2)  ? t : 0.0f, B);
        t = __shfl_up(B, 4, 64);  B = fmaf(A32,  (lane >= 4)  ? t : 0.0f, B);
        t = __shfl_up(B, 8, 64);  B = fmaf(A64,  (lane >= 8)  ? t : 0.0f, B);
        t = __shfl_up(B, 16, 64); B = fmaf(A128, (lane >= 16) ? t : 0.0f, B);
        t = __shfl_up(B, 32, 64); B = fmaf(A256, (lane >= 32) ? t : 0.0f, B);

        // n-state entering this lane's segment.
        float bp = __shfl_up(B, 1, 64);
        float n = fmaf(powAl, carry, (lane >= 1) ? bp : 0.0f);

        // Carry for next batch (1 broadcast + 1 fma per iter).
        float b63 = __shfl(B, 63, 64);
        carry = fmaf(A512, carry, b63);

        // Per-element recompute + PCEN nonlinearity (single-inst trans ops).
        float4 o0, o1;
        n = fmaf(A, n, v0.x);
        o0.x = __builtin_amdgcn_sqrtf(fmaf(v0.x, __builtin_amdgcn_exp2f(NA * __builtin_amdgcn_logf(fmaf(S, n, EPS))), 2.0f)) - SQRT2;
        n = fmaf(A, n, v0.y);
        o0.y = __builtin_amdgcn_sqrtf(fmaf(v0.y, __builtin_amdgcn_exp2f(NA * __builtin_amdgcn_logf(fmaf(S, n, EPS))), 2.0f)) - SQRT2;
        n = fmaf(A, n, v0.z);
        o0.z = __builtin_amdgcn_sqrtf(fmaf(v0.z, __builtin_amdgcn_exp2f(NA * __builtin_amdgcn_logf(fmaf(S, n, EPS))), 2.0f)) - SQRT2;
        n = fmaf(A, n, v0.w);
        o0.w = __builtin_amdgcn_sqrtf(fmaf(v0.w, __builtin_amdgcn_exp2f(NA * __builtin_amdgcn_logf(fmaf(S, n, EPS))), 2.0f)) - SQRT2;
        n = fmaf(A, n, v1.x);
        o1.x = __builtin_amdgcn_sqrtf(fmaf(v1.x, __builtin_amdgcn_exp2f(NA * __builtin_amdgcn_logf(fmaf(S, n, EPS))), 2.0f)) - SQRT2;
        n = fmaf(A, n, v1.y);
        o1.y = __builtin_amdgcn_sqrtf(fmaf(v1.y, __builtin_amdgcn_exp2f(NA * __builtin_amdgcn_logf(fmaf(S, n, EPS))), 2.0f)) - SQRT2;
        n = fmaf(A, n, v1.z);
        o1.z = __builtin_amdgcn_sqrtf(fmaf(v1.z, __builtin_amdgcn_exp2f(NA * __builtin_amdgcn_logf(fmaf(S, n, EPS))), 2.0f)) - SQRT2;
        n = fmaf(A, n, v1.w);
        o1.w = __builtin_amdgcn_sqrtf(fmaf(v1.w, __builtin_amdgcn_exp2f(NA * __builtin_amdgcn_logf(fmaf(S, n, EPS))), 2.0f)) - SQRT2;

        if (active) { oi[it * 128] = o0; oi[it * 128 + 1] = o1; }
    }
}

extern "C" void kernel_launch(void* const* d_in, const int* in_sizes, int n_in,
                              void* d_out, int out_size, void* d_ws, size_t ws_size,
                              hipStream_t stream) {
    const float* x = (const float*)d_in[0];
    float* out = (float*)d_out;
    // One wave per row: 8192 waves, 256 threads/block -> 2048 blocks.
    const int block = 256;
    const int grid = (NROWS * 64) / block;
    pcen_kernel<<<grid, block, 0, stream>>>(x, out);
}

// Round 5
// 48.358 us; speedup vs baseline: 1.1994x; 1.1994x over previous
//
#include <hip/hip_runtime.h>

// PCEN over x[B=64, M=128, T=4000] fp32, T contiguous.
// n_t = A*n_{t-1} + x_t (n = m/S) ; pcen = sqrt(x*(S*n+eps)^-0.98 + 2) - sqrt(2)
//
// One wave per row, 256 contiguous timesteps/iter, lane l owns elems [4l,4l+4)
// (wave load/store = 1KB fully packed -> perfect coalescing, the R4 lesson).
// Weighted inclusive scan done entirely with DPP (no LDS crossbar ops):
//   row_shr:1/2/4/8 with weights A4^d, then row_bcast15 (rows 1,3) and
//   row_bcast31 (rows 2,3) with per-lane geometric weights.
// Exclusive value recovered as (B - B0)/A4; carry via v_readlane -> SGPR.

#define TT     4000
#define NROWS  8192   // 64*128
#define NFULL  15     // 15*256 full batches
#define TAILL  40     // tail: 160 elems = 40 lanes * 4

// dpp_ctrl encodings (gfx9): row_shr:N = 0x110|N, row_bcast15=0x142, row_bcast31=0x143
#define DPPF(x, ctrl, rmask) \
    __int_as_float(__builtin_amdgcn_update_dpp(0, __float_as_int(x), (ctrl), (rmask), 0xf, false))

__global__ __launch_bounds__(256, 8) void pcen_kernel(const float* __restrict__ x,
                                                      float* __restrict__ out) {
    const int wid  = (blockIdx.x * blockDim.x + threadIdx.x) >> 6;  // = row
    const int lane = threadIdx.x & 63;

    const float S = 0.025f, A = 0.975f, EPS = 1e-6f, NA = -0.98f;
    const float SQRT2 = 1.41421356237f;

    const float A2   = A * A;
    const float A4   = A2 * A2;
    const float A8   = A4 * A4;
    const float A16  = A8 * A8;
    const float A32  = A16 * A16;
    const float A64  = A32 * A32;
    const float A128 = A64 * A64;
    const float A256 = A128 * A128;
    const float INVA4 = 1.0f / A4;

    // powAl = A^(4*lane)  (carry decay into this lane's segment)
    float powAl = 1.0f;
    if (lane & 1)  powAl *= A4;
    if (lane & 2)  powAl *= A8;
    if (lane & 4)  powAl *= A16;
    if (lane & 8)  powAl *= A32;
    if (lane & 16) powAl *= A64;
    if (lane & 32) powAl *= A128;

    // Per-lane weights for the DPP row-bcast combine steps.
    // bcast15 -> receiving lane distance = (lane&15)+1 ; bcast31 -> (lane&31)+1
    float p15 = 1.0f;
    if (lane & 1) p15 *= A4;
    if (lane & 2) p15 *= A8;
    if (lane & 4) p15 *= A16;
    if (lane & 8) p15 *= A32;
    float w15 = A4 * p15;                         // A^(4*((lane&15)+1))
    float w31 = (lane & 16) ? (w15 * A64) : w15;  // A^(4*((lane&31)+1))

    const float4* xi = (const float4*)(x   + (long)wid * TT) + lane;
    float4*       oi = (float4*)      (out + (long)wid * TT) + lane;

    float carry = 0.0f;  // wave-uniform n-state entering the batch

    #pragma unroll 2
    for (int it = 0; it <= NFULL; ++it) {
        const bool active = (it < NFULL) | (lane < TAILL);
        float4 v = make_float4(0.f, 0.f, 0.f, 0.f);
        if (active) v = xi[it * 64];

        // Lane-local aggregate from 0 (n-space).
        float b = v.x;
        b = fmaf(A, b, v.y);
        b = fmaf(A, b, v.z);
        float B0 = fmaf(A, b, v.w);
        float B = B0;

        // Weighted inclusive wave scan, all-DPP.
        B = fmaf(A4,  DPPF(B, 0x111, 0xf), B);   // row_shr:1
        B = fmaf(A8,  DPPF(B, 0x112, 0xf), B);   // row_shr:2
        B = fmaf(A16, DPPF(B, 0x114, 0xf), B);   // row_shr:4
        B = fmaf(A32, DPPF(B, 0x118, 0xf), B);   // row_shr:8
        B = fmaf(w15, DPPF(B, 0x142, 0xa), B);   // row_bcast15 -> rows 1,3
        B = fmaf(w31, DPPF(B, 0x143, 0xc), B);   // row_bcast31 -> rows 2,3

        // Exclusive (previous-lane inclusive) without a shuffle: B = B0 + A4*excl
        float bp = (B - B0) * INVA4;

        // n-state entering this lane's 4 elements.
        float n = fmaf(powAl, carry, bp);

        // Carry for next batch: lane63's inclusive total, via readlane (SGPR).
        float b63 = __int_as_float(__builtin_amdgcn_readlane(__float_as_int(B), 63));
        carry = fmaf(A256, carry, b63);

        // Per-element recompute + PCEN nonlinearity (single-inst trans).
        float4 o;
        n = fmaf(A, n, v.x);
        o.x = __builtin_amdgcn_sqrtf(fmaf(v.x, __builtin_amdgcn_exp2f(NA * __builtin_amdgcn_logf(fmaf(S, n, EPS))), 2.0f)) - SQRT2;
        n = fmaf(A, n, v.y);
        o.y = __builtin_amdgcn_sqrtf(fmaf(v.y, __builtin_amdgcn_exp2f(NA * __builtin_amdgcn_logf(fmaf(S, n, EPS))), 2.0f)) - SQRT2;
        n = fmaf(A, n, v.z);
        o.z = __builtin_amdgcn_sqrtf(fmaf(v.z, __builtin_amdgcn_exp2f(NA * __builtin_amdgcn_logf(fmaf(S, n, EPS))), 2.0f)) - SQRT2;
        n = fmaf(A, n, v.w);
        o.w = __builtin_amdgcn_sqrtf(fmaf(v.w, __builtin_amdgcn_exp2f(NA * __builtin_amdgcn_logf(fmaf(S, n, EPS))), 2.0f)) - SQRT2;

        if (active) oi[it * 64] = o;
    }
}

extern "C" void kernel_launch(void* const* d_in, const int* in_sizes, int n_in,
                              void* d_out, int out_size, void* d_ws, size_t ws_size,
                              hipStream_t stream) {
    const float* x = (const float*)d_in[0];
    float* out = (float*)d_out;
    const int block = 256;
    const int grid = (NROWS * 64) / block;  // 8192 waves = 1 per row
    pcen_kernel<<<grid, block, 0, stream>>>(x, out);
}

// Round 7
// 45.438 us; speedup vs baseline: 1.2765x; 1.0643x over previous
//
#include <hip/hip_runtime.h>

// PCEN over x[B=64, M=128, T=4000] fp32, T contiguous.
// n_t = A*n_{t-1} + x_t (n = m/S) ; pcen = sqrt(x*(S*n+eps)^-0.98 + 2) - sqrt(2)
//
// One wave per row, 256 contiguous timesteps/iter, lane l owns elems [4l,4l+4)
// (wave load/store = 1KB fully packed -> perfect coalescing).
// Weighted inclusive scan entirely with DPP (no LDS crossbar ops).
// R6: NONTEMPORAL stores (via native clang vector type) -> output doesn't
// allocate in L3, so the 131MB input stays L3-resident across graph replays.

#define TT     4000
#define NROWS  8192   // 64*128
#define NFULL  15     // 15*256 full batches
#define TAILL  40     // tail: 160 elems = 40 lanes * 4

typedef float f32x4 __attribute__((ext_vector_type(4)));

// dpp_ctrl encodings (gfx9): row_shr:N = 0x110|N, row_bcast15=0x142, row_bcast31=0x143
#define DPPF(x, ctrl, rmask) \
    __int_as_float(__builtin_amdgcn_update_dpp(0, __float_as_int(x), (ctrl), (rmask), 0xf, false))

__global__ __launch_bounds__(256, 8) void pcen_kernel(const float* __restrict__ x,
                                                      float* __restrict__ out) {
    const int wid  = (blockIdx.x * blockDim.x + threadIdx.x) >> 6;  // = row
    const int lane = threadIdx.x & 63;

    const float S = 0.025f, A = 0.975f, EPS = 1e-6f, NA = -0.98f;
    const float SQRT2 = 1.41421356237f;

    const float A2   = A * A;
    const float A4   = A2 * A2;
    const float A8   = A4 * A4;
    const float A16  = A8 * A8;
    const float A32  = A16 * A16;
    const float A64  = A32 * A32;
    const float A128 = A64 * A64;
    const float A256 = A128 * A128;
    const float INVA4 = 1.0f / A4;

    // powAl = A^(4*lane)  (carry decay into this lane's segment)
    float powAl = 1.0f;
    if (lane & 1)  powAl *= A4;
    if (lane & 2)  powAl *= A8;
    if (lane & 4)  powAl *= A16;
    if (lane & 8)  powAl *= A32;
    if (lane & 16) powAl *= A64;
    if (lane & 32) powAl *= A128;

    // Per-lane weights for the DPP row-bcast combine steps.
    float p15 = 1.0f;
    if (lane & 1) p15 *= A4;
    if (lane & 2) p15 *= A8;
    if (lane & 4) p15 *= A16;
    if (lane & 8) p15 *= A32;
    float w15 = A4 * p15;                         // A^(4*((lane&15)+1))
    float w31 = (lane & 16) ? (w15 * A64) : w15;  // A^(4*((lane&31)+1))

    const float4* xi = (const float4*)(x   + (long)wid * TT) + lane;
    f32x4*        oi = (f32x4*)      (out + (long)wid * TT) + lane;

    float carry = 0.0f;  // wave-uniform n-state entering the batch

    #pragma unroll 2
    for (int it = 0; it <= NFULL; ++it) {
        const bool active = (it < NFULL) | (lane < TAILL);
        float4 v = make_float4(0.f, 0.f, 0.f, 0.f);
        if (active) v = xi[it * 64];

        // Lane-local aggregate from 0 (n-space).
        float b = v.x;
        b = fmaf(A, b, v.y);
        b = fmaf(A, b, v.z);
        float B0 = fmaf(A, b, v.w);
        float B = B0;

        // Weighted inclusive wave scan, all-DPP.
        B = fmaf(A4,  DPPF(B, 0x111, 0xf), B);   // row_shr:1
        B = fmaf(A8,  DPPF(B, 0x112, 0xf), B);   // row_shr:2
        B = fmaf(A16, DPPF(B, 0x114, 0xf), B);   // row_shr:4
        B = fmaf(A32, DPPF(B, 0x118, 0xf), B);   // row_shr:8
        B = fmaf(w15, DPPF(B, 0x142, 0xa), B);   // row_bcast15 -> rows 1,3
        B = fmaf(w31, DPPF(B, 0x143, 0xc), B);   // row_bcast31 -> rows 2,3

        // Exclusive (previous-lane inclusive) without a shuffle.
        float bp = (B - B0) * INVA4;

        // n-state entering this lane's 4 elements.
        float n = fmaf(powAl, carry, bp);

        // Carry for next batch: lane63's inclusive total, via readlane (SGPR).
        float b63 = __int_as_float(__builtin_amdgcn_readlane(__float_as_int(B), 63));
        carry = fmaf(A256, carry, b63);

        // Per-element recompute + PCEN nonlinearity (single-inst trans).
        f32x4 o;
        n = fmaf(A, n, v.x);
        o.x = __builtin_amdgcn_sqrtf(fmaf(v.x, __builtin_amdgcn_exp2f(NA * __builtin_amdgcn_logf(fmaf(S, n, EPS))), 2.0f)) - SQRT2;
        n = fmaf(A, n, v.y);
        o.y = __builtin_amdgcn_sqrtf(fmaf(v.y, __builtin_amdgcn_exp2f(NA * __builtin_amdgcn_logf(fmaf(S, n, EPS))), 2.0f)) - SQRT2;
        n = fmaf(A, n, v.z);
        o.z = __builtin_amdgcn_sqrtf(fmaf(v.z, __builtin_amdgcn_exp2f(NA * __builtin_amdgcn_logf(fmaf(S, n, EPS))), 2.0f)) - SQRT2;
        n = fmaf(A, n, v.w);
        o.w = __builtin_amdgcn_sqrtf(fmaf(v.w, __builtin_amdgcn_exp2f(NA * __builtin_amdgcn_logf(fmaf(S, n, EPS))), 2.0f)) - SQRT2;

        if (active) __builtin_nontemporal_store(o, &oi[it * 64]);
    }
}

extern "C" void kernel_launch(void* const* d_in, const int* in_sizes, int n_in,
                              void* d_out, int out_size, void* d_ws, size_t ws_size,
                              hipStream_t stream) {
    const float* x = (const float*)d_in[0];
    float* out = (float*)d_out;
    const int block = 256;
    const int grid = (NROWS * 64) / block;  // 8192 waves = 1 per row
    pcen_kernel<<<grid, block, 0, stream>>>(x, out);
}

// Round 8
// 43.939 us; speedup vs baseline: 1.3201x; 1.0341x over previous
//
#include <hip/hip_runtime.h>

// PCEN over x[B=64, M=128, T=4000] fp32, T contiguous.
// n_t = A*n_{t-1} + x_t (n = m/S) ; pcen = sqrt(x*(S*n+eps)^-0.98 + 2) - sqrt(2)
//
// One wave per row, 256 contiguous timesteps/iter (lane l owns [4l,4l+4)).
// All-DPP weighted inclusive scan; NT stores (output doesn't pollute L3).
// R8: fully-unrolled loop + explicit 4-deep rotating load prefetch (static
// indices only) -> 4 loads in flight per wave instead of 1, hiding L3/HBM
// read latency behind the scan pipeline.

#define TT     4000
#define NROWS  8192   // 64*128
#define NIT    16     // 15 full batches + 1 tail batch
#define NFULL  15
#define TAILL  40     // tail: 160 elems = 40 lanes * 4
#define PF     4      // prefetch depth

typedef float f32x4 __attribute__((ext_vector_type(4)));

// dpp_ctrl (gfx9): row_shr:N = 0x110|N, row_bcast15=0x142, row_bcast31=0x143
#define DPPF(x, ctrl, rmask) \
    __int_as_float(__builtin_amdgcn_update_dpp(0, __float_as_int(x), (ctrl), (rmask), 0xf, false))

__global__ __launch_bounds__(256, 8) void pcen_kernel(const float* __restrict__ x,
                                                      float* __restrict__ out) {
    const int wid  = (blockIdx.x * blockDim.x + threadIdx.x) >> 6;  // = row
    const int lane = threadIdx.x & 63;

    const float S = 0.025f, A = 0.975f, EPS = 1e-6f, NA = -0.98f;
    const float SQRT2 = 1.41421356237f;

    const float A2   = A * A;
    const float A4   = A2 * A2;
    const float A8   = A4 * A4;
    const float A16  = A8 * A8;
    const float A32  = A16 * A16;
    const float A64  = A32 * A32;
    const float A128 = A64 * A64;
    const float A256 = A128 * A128;
    const float INVA4 = 1.0f / A4;

    // powAl = A^(4*lane)
    float powAl = 1.0f;
    if (lane & 1)  powAl *= A4;
    if (lane & 2)  powAl *= A8;
    if (lane & 4)  powAl *= A16;
    if (lane & 8)  powAl *= A32;
    if (lane & 16) powAl *= A64;
    if (lane & 32) powAl *= A128;

    // Per-lane weights for the DPP row-bcast combine steps.
    float p15 = 1.0f;
    if (lane & 1) p15 *= A4;
    if (lane & 2) p15 *= A8;
    if (lane & 4) p15 *= A16;
    if (lane & 8) p15 *= A32;
    float w15 = A4 * p15;                         // A^(4*((lane&15)+1))
    float w31 = (lane & 16) ? (w15 * A64) : w15;  // A^(4*((lane&31)+1))

    const float4* xi = (const float4*)(x   + (long)wid * TT) + lane;
    f32x4*        oi = (f32x4*)      (out + (long)wid * TT) + lane;

    const bool tail_act = (lane < TAILL);

    float carry = 0.0f;
    float4 vbuf[PF];

    // Prologue: fill the prefetch pipe (all indices static).
    #pragma unroll
    for (int p = 0; p < PF; ++p) {
        bool act = (p < NFULL) | tail_act;
        float4 r = make_float4(0.f, 0.f, 0.f, 0.f);
        if (act) r = xi[p * 64];
        vbuf[p] = r;
    }

    #pragma unroll
    for (int it = 0; it < NIT; ++it) {
        float4 v = vbuf[it % PF];

        // Prefetch it+PF (static index since fully unrolled).
        if (it + PF < NIT) {
            bool act = ((it + PF) < NFULL) | tail_act;
            float4 r = make_float4(0.f, 0.f, 0.f, 0.f);
            if (act) r = xi[(it + PF) * 64];
            vbuf[it % PF] = r;
        }

        // Lane-local aggregate from 0 (n-space).
        float b = v.x;
        b = fmaf(A, b, v.y);
        b = fmaf(A, b, v.z);
        float B0 = fmaf(A, b, v.w);
        float B = B0;

        // Weighted inclusive wave scan, all-DPP.
        B = fmaf(A4,  DPPF(B, 0x111, 0xf), B);   // row_shr:1
        B = fmaf(A8,  DPPF(B, 0x112, 0xf), B);   // row_shr:2
        B = fmaf(A16, DPPF(B, 0x114, 0xf), B);   // row_shr:4
        B = fmaf(A32, DPPF(B, 0x118, 0xf), B);   // row_shr:8
        B = fmaf(w15, DPPF(B, 0x142, 0xa), B);   // row_bcast15 -> rows 1,3
        B = fmaf(w31, DPPF(B, 0x143, 0xc), B);   // row_bcast31 -> rows 2,3

        // Exclusive (previous-lane inclusive) without a shuffle.
        float bp = (B - B0) * INVA4;

        // n-state entering this lane's 4 elements.
        float n = fmaf(powAl, carry, bp);

        // Carry for next batch via readlane (SGPR broadcast).
        float b63 = __int_as_float(__builtin_amdgcn_readlane(__float_as_int(B), 63));
        carry = fmaf(A256, carry, b63);

        // Per-element recompute + PCEN nonlinearity (single-inst trans).
        f32x4 o;
        n = fmaf(A, n, v.x);
        o.x = __builtin_amdgcn_sqrtf(fmaf(v.x, __builtin_amdgcn_exp2f(NA * __builtin_amdgcn_logf(fmaf(S, n, EPS))), 2.0f)) - SQRT2;
        n = fmaf(A, n, v.y);
        o.y = __builtin_amdgcn_sqrtf(fmaf(v.y, __builtin_amdgcn_exp2f(NA * __builtin_amdgcn_logf(fmaf(S, n, EPS))), 2.0f)) - SQRT2;
        n = fmaf(A, n, v.z);
        o.z = __builtin_amdgcn_sqrtf(fmaf(v.z, __builtin_amdgcn_exp2f(NA * __builtin_amdgcn_logf(fmaf(S, n, EPS))), 2.0f)) - SQRT2;
        n = fmaf(A, n, v.w);
        o.w = __builtin_amdgcn_sqrtf(fmaf(v.w, __builtin_amdgcn_exp2f(NA * __builtin_amdgcn_logf(fmaf(S, n, EPS))), 2.0f)) - SQRT2;

        bool act = (it < NFULL) | tail_act;
        if (act) __builtin_nontemporal_store(o, &oi[it * 64]);
    }
}

extern "C" void kernel_launch(void* const* d_in, const int* in_sizes, int n_in,
                              void* d_out, int out_size, void* d_ws, size_t ws_size,
                              hipStream_t stream) {
    const float* x = (const float*)d_in[0];
    float* out = (float*)d_out;
    const int block = 256;
    const int grid = (NROWS * 64) / block;  // 8192 waves = 1 per row
    pcen_kernel<<<grid, block, 0, stream>>>(x, out);
}